// Round 5
// baseline (237.274 us; speedup 1.0000x reference)
//
#include <hip/hip_runtime.h>

#define DXYZ 128
#define NVERT (DXYZ * DXYZ * DXYZ)     // 2097152 voxels per (cloud,batch) grid
#define BIN 16                          // region/bin edge in voxels
#define SBINS 512                       // spatial bins per grid (8^3)
#define CHUNK 1024                      // points per hist/scatter block
#define MAXCHUNKS 1024                  // chunkscan LDS capacity

// Record: 8 bytes.
//   lo = fx16 | fy16<<16          (frac in 1/65536 fixed point)
//   hi = fz16 | (lx+1)<<16 | (ly+1)<<21 | (lz+1)<<26
// lx/ly/lz are the lower-corner voxel coords relative to the record's bin
// origin, in [-1, 15] (-1 happens for duplicated records in a +1 neighbor bin).

// ---------------- Pass 1: per-chunk LDS histogram ----------------
// bcnt layout: [key][chunk], key = cb*SBINS + sbin.
__global__ __launch_bounds__(256) void hist2_kernel(
    const float* __restrict__ p0, const float* __restrict__ p1,
    unsigned* __restrict__ bcnt,
    int N, int B, int nchunks, int dup)
{
    __shared__ unsigned h[SBINS];
    for (int i = threadIdx.x; i < SBINS; i += 256) h[i] = 0u;
    __syncthreads();

    int blk = blockIdx.x;
    int cb = blk / nchunks;            // cloud*B + batch
    int c  = blk - cb * nchunks;       // chunk within slice
    const float* p = (cb < B ? p0 : p1) +
                     ((size_t)(cb % B) * N + (size_t)c * CHUNK) * 3;

    for (int i = threadIdx.x; i < CHUNK; i += 256) {
        float px = p[3*i+0] * 64.0f;
        float py = p[3*i+1] * 64.0f;
        float pz = p[3*i+2] * 64.0f;
        int ix = (int)floorf(px) + 64;
        int iy = (int)floorf(py) + 64;
        int iz = (int)floorf(pz) + 64;
        int bx0 = ix >> 4, by0 = iy >> 4, bz0 = iz >> 4;
        int bx1 = (ix+1) >> 4, by1 = (iy+1) >> 4, bz1 = (iz+1) >> 4;
        if (!dup) { bx1 = bx0; by1 = by0; bz1 = bz0; }
        for (int bx = bx0; bx <= bx1; ++bx)
            for (int by = by0; by <= by1; ++by)
                for (int bz = bz0; bz <= bz1; ++bz)
                    atomicAdd(&h[(bx << 6) + (by << 3) + bz], 1u);
    }
    __syncthreads();

    for (int k = threadIdx.x; k < SBINS; k += 256)
        bcnt[(size_t)(cb * SBINS + k) * nchunks + c] = h[k];
}

// ---------------- Pass 2a: per-key exclusive scan over chunks (in place) ----
__global__ __launch_bounds__(256) void chunkscan_kernel(
    unsigned* __restrict__ bcnt,         // [key][chunk] -> exclusive scan
    unsigned* __restrict__ keytotal,     // [key]
    int nchunks)
{
    __shared__ unsigned s[MAXCHUNKS];
    int key = blockIdx.x;
    unsigned* row = bcnt + (size_t)key * nchunks;

    for (int i = threadIdx.x; i < nchunks; i += 256) s[i] = row[i];
    __syncthreads();
    for (int off = 1; off < nchunks; off <<= 1) {
        unsigned v[MAXCHUNKS / 256];
        int nv = 0;
        for (int i = threadIdx.x; i < nchunks; i += 256)
            v[nv++] = (i >= off) ? s[i - off] : 0u;
        __syncthreads();
        nv = 0;
        for (int i = threadIdx.x; i < nchunks; i += 256)
            s[i] += v[nv++];
        __syncthreads();
    }
    for (int i = threadIdx.x; i < nchunks; i += 256)
        row[i] = (i == 0) ? 0u : s[i - 1];
    if (threadIdx.x == 0) keytotal[key] = s[nchunks - 1];
}

// ---------------- Pass 2b: exclusive scan over keys (1 block) ----------------
__global__ __launch_bounds__(1024) void scan_kernel(
    const unsigned* __restrict__ counts,
    unsigned* __restrict__ key_start,   // nkeys+1
    int nkeys)
{
    __shared__ unsigned part[1024];
    int tid = threadIdx.x;
    int chunk = (nkeys + 1023) / 1024;
    int lo = tid * chunk;
    unsigned s = 0;
    for (int i = 0; i < chunk; ++i) {
        int k = lo + i;
        if (k < nkeys) s += counts[k];
    }
    part[tid] = s;
    __syncthreads();
    for (int off = 1; off < 1024; off <<= 1) {
        unsigned v = (tid >= off) ? part[tid - off] : 0u;
        __syncthreads();
        part[tid] += v;
        __syncthreads();
    }
    unsigned run = (tid == 0) ? 0u : part[tid - 1];
    for (int i = 0; i < chunk; ++i) {
        int k = lo + i;
        if (k < nkeys) {
            key_start[k] = run;
            run += counts[k];
        }
    }
    if (tid == 1023) key_start[nkeys] = run;
}

// ---------------- Pass 3: scatter via LDS cursors ----------------
__global__ __launch_bounds__(256) void scatter2_kernel(
    const float* __restrict__ p0, const float* __restrict__ p1,
    const unsigned* __restrict__ bscan,     // [key][chunk] exclusive per key
    const unsigned* __restrict__ keystart,  // [key]
    uint2* __restrict__ sorted, unsigned cap,
    int N, int B, int nchunks, int dup)
{
    __shared__ unsigned cur[SBINS];
    int blk = blockIdx.x;
    int cb = blk / nchunks;
    int c  = blk - cb * nchunks;
    for (int k = threadIdx.x; k < SBINS; k += 256) {
        int key = cb * SBINS + k;
        cur[k] = keystart[key] + bscan[(size_t)key * nchunks + c];
    }
    __syncthreads();

    const float* p = (cb < B ? p0 : p1) +
                     ((size_t)(cb % B) * N + (size_t)c * CHUNK) * 3;
    for (int i = threadIdx.x; i < CHUNK; i += 256) {
        float px = p[3*i+0] * 64.0f;
        float py = p[3*i+1] * 64.0f;
        float pz = p[3*i+2] * 64.0f;
        float lx = floorf(px), ly = floorf(py), lz = floorf(pz);
        int ix = (int)lx + 64, iy = (int)ly + 64, iz = (int)lz + 64;
        unsigned ex = min((unsigned)((px - lx) * 65536.0f), 65535u);
        unsigned ey = min((unsigned)((py - ly) * 65536.0f), 65535u);
        unsigned ez = min((unsigned)((pz - lz) * 65536.0f), 65535u);
        unsigned lo = ex | (ey << 16);
        int bx0 = ix >> 4, by0 = iy >> 4, bz0 = iz >> 4;
        int bx1 = (ix+1) >> 4, by1 = (iy+1) >> 4, bz1 = (iz+1) >> 4;
        if (!dup) { bx1 = bx0; by1 = by0; bz1 = bz0; }
        for (int bx = bx0; bx <= bx1; ++bx)
            for (int by = by0; by <= by1; ++by)
                for (int bz = bz0; bz <= bz1; ++bz) {
                    unsigned llx = (unsigned)(ix - (bx << 4) + 1);  // [0,16]
                    unsigned lly = (unsigned)(iy - (by << 4) + 1);
                    unsigned llz = (unsigned)(iz - (bz << 4) + 1);
                    unsigned hi = ez | (llx << 16) | (lly << 21) | (llz << 26);
                    unsigned slot = atomicAdd(&cur[(bx << 6) + (by << 3) + bz], 1u);
                    if (slot < cap) sorted[slot] = make_uint2(lo, hi);
                }
    }
}

// ---------------- Pass 4: per-region gather + LDS accumulate ----------------
__global__ __launch_bounds__(256) void gather2_kernel(
    const uint2* __restrict__ sorted,
    const unsigned* __restrict__ keystart,
    const unsigned* __restrict__ keytotal,
    float* __restrict__ out, int dup)
{
    __shared__ float acc[BIN * BIN * BIN];  // 16 KB
    int g = blockIdx.x;
    int cb = g >> 9;
    int r = g & (SBINS - 1);
    int rx = r >> 6, ry = (r >> 3) & 7, rz = r & 7;
    int x0 = rx << 4, y0 = ry << 4, z0 = rz << 4;

    for (int i = threadIdx.x; i < BIN * BIN * BIN; i += 256) acc[i] = 0.0f;
    __syncthreads();

    int sxlo = dup ? rx : max(rx - 1, 0);
    int sylo = dup ? ry : max(ry - 1, 0);
    int szlo = dup ? rz : max(rz - 1, 0);
    int kb = cb * SBINS;
    const float inv = 1.0f / 65536.0f;
    for (int sx = sxlo; sx <= rx; ++sx)
        for (int sy = sylo; sy <= ry; ++sy)
            for (int sz = szlo; sz <= rz; ++sz) {
                int gk = kb + (sx << 6) + (sy << 3) + sz;
                unsigned s = keystart[gk], e = s + keytotal[gk];
                int obx = ((sx - rx) << 4) - 1;   // bin-origin offset - 1
                int oby = ((sy - ry) << 4) - 1;
                int obz = ((sz - rz) << 4) - 1;
                for (unsigned i = s + threadIdx.x; i < e; i += 256) {
                    uint2 rec = sorted[i];
                    float fx = (float)(rec.x & 0xffffu) * inv;
                    float fy = (float)(rec.x >> 16) * inv;
                    float fz = (float)(rec.y & 0xffffu) * inv;
                    int lx = (int)((rec.y >> 16) & 31u) + obx;
                    int ly = (int)((rec.y >> 21) & 31u) + oby;
                    int lz = (int)((rec.y >> 26) & 31u) + obz;
                    float gx[2] = {1.0f - fx, fx};
                    float gy[2] = {1.0f - fy, fy};
                    float gz[2] = {1.0f - fz, fz};
#pragma unroll
                    for (int dx = 0; dx < 2; ++dx) {
                        int cx = lx + dx;
                        if ((unsigned)cx >= (unsigned)BIN) continue;
#pragma unroll
                        for (int dy = 0; dy < 2; ++dy) {
                            int cy = ly + dy;
                            if ((unsigned)cy >= (unsigned)BIN) continue;
#pragma unroll
                            for (int dz = 0; dz < 2; ++dz) {
                                int cz = lz + dz;
                                if ((unsigned)cz >= (unsigned)BIN) continue;
                                atomicAdd(&acc[(cx * BIN + cy) * BIN + cz],
                                          gx[dx] * gy[dy] * gz[dz]);
                            }
                        }
                    }
                }
            }
    __syncthreads();

    // Coalesced epilogue: 4 lanes cover one full 64-B z-row; 4 passes of
    // 64 rows -> every 64-B line fully covered by a single wave-store.
    float* ob = out + (size_t)cb * NVERT;
    int q = threadIdx.x & 3;
#pragma unroll
    for (int pass = 0; pass < 4; ++pass) {
        int row = pass * 64 + (threadIdx.x >> 2);
        int lx = row >> 4, ly = row & 15;
        size_t o = (((size_t)(x0 + lx) * DXYZ) + (size_t)(y0 + ly)) * DXYZ
                   + z0 + q * 4;
        *(float4*)(ob + o) = *(const float4*)&acc[row * BIN + q * 4];
    }
}

// ---------------- Fallback: direct atomic splat ----------------
__global__ __launch_bounds__(256) void splat_kernel(
    const float* __restrict__ pts, float* __restrict__ out,
    int n_per_batch, int total)
{
    int t = blockIdx.x * blockDim.x + threadIdx.x;
    if (t >= total) return;
    float px = pts[3*t+0] * 64.0f, py = pts[3*t+1] * 64.0f, pz = pts[3*t+2] * 64.0f;
    float lx = floorf(px), ly = floorf(py), lz = floorf(pz);
    float fx = px - lx, fy = py - ly, fz = pz - lz;
    int ix = (int)lx + 64, iy = (int)ly + 64, iz = (int)lz + 64;
    int b = t / n_per_batch;
    float* o = out + (size_t)b * NVERT;
    size_t base = ((size_t)ix * DXYZ + (size_t)iy) * DXYZ + (size_t)iz;
    float gx[2] = {1.0f-fx, fx}, gy[2] = {1.0f-fy, fy}, gz[2] = {1.0f-fz, fz};
#pragma unroll
    for (int dx = 0; dx < 2; ++dx)
#pragma unroll
        for (int dy = 0; dy < 2; ++dy)
#pragma unroll
            for (int dz = 0; dz < 2; ++dz)
                atomicAdd(o + base + (size_t)dx * (DXYZ*DXYZ) + dy * DXYZ + dz,
                          gx[dx] * gy[dy] * gz[dz]);
}

static inline size_t align256(size_t x) { return (x + 255) & ~(size_t)255; }

extern "C" void kernel_launch(void* const* d_in, const int* in_sizes, int n_in,
                              void* d_out, int out_size, void* d_ws, size_t ws_size,
                              hipStream_t stream) {
    const float* pred = (const float*)d_in[0];
    const float* gt   = (const float*)d_in[1];
    float* out = (float*)d_out;

    int total = in_sizes[0] / 3;           // B*N points per cloud
    int B = out_size / (2 * NVERT);
    int N = total / B;
    int CB = 2 * B;
    int nchunks = N / CHUNK;
    int nkeys = CB * SBINS;
    int nblocks = CB * nchunks;
    size_t points_all = (size_t)2 * total;
    bool divisible = (N % CHUNK) == 0 && N > 0 && nchunks <= MAXCHUNKS;

    // Workspace layout
    size_t off_keytotal = 0;
    size_t off_keystart = align256((size_t)nkeys * 4);
    size_t off_bcnt     = off_keystart + align256(((size_t)nkeys + 1) * 4);
    size_t mat_bytes    = align256((size_t)nkeys * nchunks * 4);
    size_t off_sorted   = off_bcnt + mat_bytes;
    size_t cap = (ws_size > off_sorted) ? (ws_size - off_sorted) / sizeof(uint2) : 0;

    // dup path duplicates each point into every bin it touches (E[x] ~= 1.20);
    // 1.5x capacity is a huge margin for uniform inputs.
    bool can_dup   = divisible && cap >= points_all + points_all / 2;
    bool can_nodup = divisible && cap >= points_all;

    if (!can_nodup) {
        hipMemsetAsync(d_out, 0, (size_t)out_size * sizeof(float), stream);
        int blocks = (total + 255) / 256;
        splat_kernel<<<blocks, 256, 0, stream>>>(pred, out, N, total);
        splat_kernel<<<blocks, 256, 0, stream>>>(gt, out + (size_t)B * NVERT, N, total);
        return;
    }
    int dup = can_dup ? 1 : 0;

    char* ws = (char*)d_ws;
    unsigned* keytotal = (unsigned*)(ws + off_keytotal);
    unsigned* keystart = (unsigned*)(ws + off_keystart);
    unsigned* bcnt     = (unsigned*)(ws + off_bcnt);
    uint2*    sorted   = (uint2*)(ws + off_sorted);

    hist2_kernel<<<nblocks, 256, 0, stream>>>(pred, gt, bcnt, N, B, nchunks, dup);
    chunkscan_kernel<<<nkeys, 256, 0, stream>>>(bcnt, keytotal, nchunks);
    scan_kernel<<<1, 1024, 0, stream>>>(keytotal, keystart, nkeys);
    scatter2_kernel<<<nblocks, 256, 0, stream>>>(pred, gt, bcnt, keystart, sorted,
                                                 (unsigned)cap, N, B, nchunks, dup);
    gather2_kernel<<<nkeys, 256, 0, stream>>>(sorted, keystart, keytotal, out, dup);
}

// Round 7
// 199.521 us; speedup vs baseline: 1.1892x; 1.1892x over previous
//
#include <hip/hip_runtime.h>

#define DXYZ 128
#define NVERT (DXYZ * DXYZ * DXYZ)     // 2097152 voxels per (cloud,batch) grid
#define SBINS 128                       // bins per grid: 16(x) x 8(y), full z
#define RX 8                            // region x-extent  (bx = ix>>3, 16 bins)
#define RY 16                           // region y-extent  (by = iy>>4, 8 bins)
#define CHUNK 4096                      // points per hist/scatter block
#define PTHREADS 512                    // threads for hist/scatter blocks
#define MAXCHUNKS 1024                  // chunkscan LDS capacity

typedef float nf4 __attribute__((ext_vector_type(4)));  // native vec for builtins

// Record: 8 bytes.
//   lo = fx16 | fy16<<16                        (frac, 1/65536 fixed point)
//   hi = fz16 | (lx+1)<<16 | (ly+1)<<20 | iz<<25
// lx in [-1,7] rel. to bin x-origin, ly in [-1,15] rel. to bin y-origin,
// iz = absolute z voxel (7 bits). Regions span full z -> no z binning.

// ---------------- Pass 1: per-chunk LDS histogram ----------------
// bcnt layout: [key][chunk], key = cb*SBINS + (bx*8+by).
__global__ __launch_bounds__(PTHREADS) void hist2_kernel(
    const float* __restrict__ p0, const float* __restrict__ p1,
    unsigned* __restrict__ bcnt,
    int N, int B, int nchunks, int dup)
{
    __shared__ unsigned h[SBINS];
    for (int i = threadIdx.x; i < SBINS; i += PTHREADS) h[i] = 0u;
    __syncthreads();

    int blk = blockIdx.x;
    int cb = blk / nchunks;            // cloud*B + batch
    int c  = blk - cb * nchunks;       // chunk within slice
    const float* p = (cb < B ? p0 : p1) +
                     ((size_t)(cb % B) * N + (size_t)c * CHUNK) * 3;

    for (int i = threadIdx.x; i < CHUNK; i += PTHREADS) {
        float px = p[3*i+0] * 64.0f;
        float py = p[3*i+1] * 64.0f;
        int ix = (int)floorf(px) + 64;
        int iy = (int)floorf(py) + 64;
        int bx0 = ix >> 3, by0 = iy >> 4;
        int bx1 = (ix+1) >> 3, by1 = (iy+1) >> 4;
        if (!dup) { bx1 = bx0; by1 = by0; }
        for (int bx = bx0; bx <= bx1; ++bx)
            for (int by = by0; by <= by1; ++by)
                atomicAdd(&h[(bx << 3) + by], 1u);
    }
    __syncthreads();

    for (int k = threadIdx.x; k < SBINS; k += PTHREADS)
        bcnt[(size_t)(cb * SBINS + k) * nchunks + c] = h[k];
}

// ---------------- Pass 2a: per-key exclusive scan over chunks (in place) ----
__global__ __launch_bounds__(256) void chunkscan_kernel(
    unsigned* __restrict__ bcnt,         // [key][chunk] -> exclusive scan
    unsigned* __restrict__ keytotal,     // [key]
    int nchunks)
{
    __shared__ unsigned s[MAXCHUNKS];
    int key = blockIdx.x;
    unsigned* row = bcnt + (size_t)key * nchunks;

    for (int i = threadIdx.x; i < nchunks; i += 256) s[i] = row[i];
    __syncthreads();
    for (int off = 1; off < nchunks; off <<= 1) {
        unsigned v[MAXCHUNKS / 256];
        int nv = 0;
        for (int i = threadIdx.x; i < nchunks; i += 256)
            v[nv++] = (i >= off) ? s[i - off] : 0u;
        __syncthreads();
        nv = 0;
        for (int i = threadIdx.x; i < nchunks; i += 256)
            s[i] += v[nv++];
        __syncthreads();
    }
    for (int i = threadIdx.x; i < nchunks; i += 256)
        row[i] = (i == 0) ? 0u : s[i - 1];
    if (threadIdx.x == 0) keytotal[key] = s[nchunks - 1];
}

// ---------------- Pass 2b: exclusive scan over keys (1 block) ----------------
__global__ __launch_bounds__(1024) void scan_kernel(
    const unsigned* __restrict__ counts,
    unsigned* __restrict__ key_start,   // nkeys+1
    int nkeys)
{
    __shared__ unsigned part[1024];
    int tid = threadIdx.x;
    int chunk = (nkeys + 1023) / 1024;
    int lo = tid * chunk;
    unsigned s = 0;
    for (int i = 0; i < chunk; ++i) {
        int k = lo + i;
        if (k < nkeys) s += counts[k];
    }
    part[tid] = s;
    __syncthreads();
    for (int off = 1; off < 1024; off <<= 1) {
        unsigned v = (tid >= off) ? part[tid - off] : 0u;
        __syncthreads();
        part[tid] += v;
        __syncthreads();
    }
    unsigned run = (tid == 0) ? 0u : part[tid - 1];
    for (int i = 0; i < chunk; ++i) {
        int k = lo + i;
        if (k < nkeys) {
            key_start[k] = run;
            run += counts[k];
        }
    }
    if (tid == 1023) key_start[nkeys] = run;
}

// ---------------- Pass 3: scatter via LDS cursors ----------------
__global__ __launch_bounds__(PTHREADS) void scatter2_kernel(
    const float* __restrict__ p0, const float* __restrict__ p1,
    const unsigned* __restrict__ bscan,     // [key][chunk] exclusive per key
    const unsigned* __restrict__ keystart,  // [key]
    uint2* __restrict__ sorted, unsigned cap,
    int N, int B, int nchunks, int dup)
{
    __shared__ unsigned cur[SBINS];
    int blk = blockIdx.x;
    int cb = blk / nchunks;
    int c  = blk - cb * nchunks;
    for (int k = threadIdx.x; k < SBINS; k += PTHREADS) {
        int key = cb * SBINS + k;
        cur[k] = keystart[key] + bscan[(size_t)key * nchunks + c];
    }
    __syncthreads();

    const float* p = (cb < B ? p0 : p1) +
                     ((size_t)(cb % B) * N + (size_t)c * CHUNK) * 3;
    for (int i = threadIdx.x; i < CHUNK; i += PTHREADS) {
        float px = p[3*i+0] * 64.0f;
        float py = p[3*i+1] * 64.0f;
        float pz = p[3*i+2] * 64.0f;
        float lx = floorf(px), ly = floorf(py), lz = floorf(pz);
        int ix = (int)lx + 64, iy = (int)ly + 64, iz = (int)lz + 64;
        unsigned ex = min((unsigned)((px - lx) * 65536.0f), 65535u);
        unsigned ey = min((unsigned)((py - ly) * 65536.0f), 65535u);
        unsigned ez = min((unsigned)((pz - lz) * 65536.0f), 65535u);
        unsigned lo = ex | (ey << 16);
        int bx0 = ix >> 3, by0 = iy >> 4;
        int bx1 = (ix+1) >> 3, by1 = (iy+1) >> 4;
        if (!dup) { bx1 = bx0; by1 = by0; }
        for (int bx = bx0; bx <= bx1; ++bx)
            for (int by = by0; by <= by1; ++by) {
                unsigned llx = (unsigned)(ix - (bx << 3) + 1);  // [0,8]
                unsigned lly = (unsigned)(iy - (by << 4) + 1);  // [0,16]
                unsigned hi = ez | (llx << 16) | (lly << 20) |
                              ((unsigned)iz << 25);
                unsigned slot = atomicAdd(&cur[(bx << 3) + by], 1u);
                if (slot < cap) sorted[slot] = make_uint2(lo, hi);
            }
    }
}

// ---------------- Pass 4: per-slab gather + LDS accumulate ----------------
// One block per (cb, bx, by): accumulates an 8 x 16 x 128 slab (64 KB LDS)
// and writes it as 8 contiguous 8-KB chunks (DRAM-friendly).
__global__ __launch_bounds__(512) void gather3_kernel(
    const uint2* __restrict__ sorted,
    const unsigned* __restrict__ keystart,
    const unsigned* __restrict__ keytotal,
    float* __restrict__ out, int dup)
{
    __shared__ float acc[RX * RY * DXYZ];  // 64 KB: [cx][cy][cz]
    int g = blockIdx.x;
    int cb = g >> 7;                       // 128 bins per grid
    int r = g & (SBINS - 1);
    int rx = r >> 3, ry = r & 7;           // rx in [0,16), ry in [0,8)
    int x0 = rx << 3, y0 = ry << 4;

    nf4* a4 = (nf4*)acc;
    nf4 z4 = {0.f, 0.f, 0.f, 0.f};
    for (int i = threadIdx.x; i < RX * RY * DXYZ / 4; i += 512) a4[i] = z4;
    __syncthreads();

    int sxlo = dup ? rx : max(rx - 1, 0);
    int sylo = dup ? ry : max(ry - 1, 0);
    int kb = cb * SBINS;
    const float inv = 1.0f / 65536.0f;
    for (int sx = sxlo; sx <= rx; ++sx)
        for (int sy = sylo; sy <= ry; ++sy) {
            int gk = kb + (sx << 3) + sy;
            unsigned s = keystart[gk], e = s + keytotal[gk];
            int obx = ((sx - rx) << 3) - 1;   // bin-origin offset - 1
            int oby = ((sy - ry) << 4) - 1;
            for (unsigned i = s + threadIdx.x; i < e; i += 512) {
                uint2 rec = sorted[i];
                float fx = (float)(rec.x & 0xffffu) * inv;
                float fy = (float)(rec.x >> 16) * inv;
                float fz = (float)(rec.y & 0xffffu) * inv;
                int lx = (int)((rec.y >> 16) & 15u) + obx;
                int ly = (int)((rec.y >> 20) & 31u) + oby;
                int zc = (int)(rec.y >> 25);
                float gx[2] = {1.0f - fx, fx};
                float gy[2] = {1.0f - fy, fy};
                float gz[2] = {1.0f - fz, fz};
#pragma unroll
                for (int dx = 0; dx < 2; ++dx) {
                    int cx = lx + dx;
                    if ((unsigned)cx >= (unsigned)RX) continue;
#pragma unroll
                    for (int dy = 0; dy < 2; ++dy) {
                        int cy = ly + dy;
                        if ((unsigned)cy >= (unsigned)RY) continue;
#pragma unroll
                        for (int dz = 0; dz < 2; ++dz) {
                            int cz = zc + dz;
                            if ((unsigned)cz >= (unsigned)DXYZ) continue;
                            atomicAdd(&acc[((cx << 4) + cy) * DXYZ + cz],
                                      gx[dx] * gy[dy] * gz[dz]);
                        }
                    }
                }
            }
        }
    __syncthreads();

    // Epilogue: 8 contiguous 8-KB chunks (one per x-plane of the slab).
    float* ob = out + (size_t)cb * NVERT;
    int tid = threadIdx.x;
#pragma unroll
    for (int cx = 0; cx < RX; ++cx) {
        size_t base = (((size_t)(x0 + cx) * DXYZ) + (size_t)y0) * DXYZ;
        nf4* dst = (nf4*)(ob + base);
        const nf4* src = (const nf4*)&acc[cx * (RY * DXYZ)];
        __builtin_nontemporal_store(src[tid], &dst[tid]);  // 512 f4 = 8 KB
    }
}

// ---------------- Fallback: direct atomic splat ----------------
__global__ __launch_bounds__(256) void splat_kernel(
    const float* __restrict__ pts, float* __restrict__ out,
    int n_per_batch, int total)
{
    int t = blockIdx.x * blockDim.x + threadIdx.x;
    if (t >= total) return;
    float px = pts[3*t+0] * 64.0f, py = pts[3*t+1] * 64.0f, pz = pts[3*t+2] * 64.0f;
    float lx = floorf(px), ly = floorf(py), lz = floorf(pz);
    float fx = px - lx, fy = py - ly, fz = pz - lz;
    int ix = (int)lx + 64, iy = (int)ly + 64, iz = (int)lz + 64;
    int b = t / n_per_batch;
    float* o = out + (size_t)b * NVERT;
    size_t base = ((size_t)ix * DXYZ + (size_t)iy) * DXYZ + (size_t)iz;
    float gx[2] = {1.0f-fx, fx}, gy[2] = {1.0f-fy, fy}, gz[2] = {1.0f-fz, fz};
#pragma unroll
    for (int dx = 0; dx < 2; ++dx)
#pragma unroll
        for (int dy = 0; dy < 2; ++dy)
#pragma unroll
            for (int dz = 0; dz < 2; ++dz)
                atomicAdd(o + base + (size_t)dx * (DXYZ*DXYZ) + dy * DXYZ + dz,
                          gx[dx] * gy[dy] * gz[dz]);
}

static inline size_t align256(size_t x) { return (x + 255) & ~(size_t)255; }

extern "C" void kernel_launch(void* const* d_in, const int* in_sizes, int n_in,
                              void* d_out, int out_size, void* d_ws, size_t ws_size,
                              hipStream_t stream) {
    const float* pred = (const float*)d_in[0];
    const float* gt   = (const float*)d_in[1];
    float* out = (float*)d_out;

    int total = in_sizes[0] / 3;           // B*N points per cloud
    int B = out_size / (2 * NVERT);
    int N = total / B;
    int CB = 2 * B;
    int nchunks = N / CHUNK;
    int nkeys = CB * SBINS;
    int nblocks = CB * nchunks;
    size_t points_all = (size_t)2 * total;
    bool divisible = (N % CHUNK) == 0 && N > 0 && nchunks <= MAXCHUNKS;

    // Workspace layout
    size_t off_keytotal = 0;
    size_t off_keystart = align256((size_t)nkeys * 4);
    size_t off_bcnt     = off_keystart + align256(((size_t)nkeys + 1) * 4);
    size_t mat_bytes    = align256((size_t)nkeys * nchunks * 4);
    size_t off_sorted   = off_bcnt + mat_bytes;
    size_t cap = (ws_size > off_sorted) ? (ws_size - off_sorted) / sizeof(uint2) : 0;

    // dup path duplicates each point into every (x,y) bin it touches
    // (E[x] ~= 1.20 for uniform inputs); 1.5x capacity is a huge margin.
    bool can_dup   = divisible && cap >= points_all + points_all / 2;
    bool can_nodup = divisible && cap >= points_all;

    if (!can_nodup) {
        (void)hipMemsetAsync(d_out, 0, (size_t)out_size * sizeof(float), stream);
        int blocks = (total + 255) / 256;
        splat_kernel<<<blocks, 256, 0, stream>>>(pred, out, N, total);
        splat_kernel<<<blocks, 256, 0, stream>>>(gt, out + (size_t)B * NVERT, N, total);
        return;
    }
    int dup = can_dup ? 1 : 0;

    char* ws = (char*)d_ws;
    unsigned* keytotal = (unsigned*)(ws + off_keytotal);
    unsigned* keystart = (unsigned*)(ws + off_keystart);
    unsigned* bcnt     = (unsigned*)(ws + off_bcnt);
    uint2*    sorted   = (uint2*)(ws + off_sorted);

    hist2_kernel<<<nblocks, PTHREADS, 0, stream>>>(pred, gt, bcnt, N, B,
                                                   nchunks, dup);
    chunkscan_kernel<<<nkeys, 256, 0, stream>>>(bcnt, keytotal, nchunks);
    scan_kernel<<<1, 1024, 0, stream>>>(keytotal, keystart, nkeys);
    scatter2_kernel<<<nblocks, PTHREADS, 0, stream>>>(pred, gt, bcnt, keystart,
                                                      sorted, (unsigned)cap,
                                                      N, B, nchunks, dup);
    gather3_kernel<<<nkeys, 512, 0, stream>>>(sorted, keystart, keytotal,
                                              out, dup);
}

// Round 8
// 198.714 us; speedup vs baseline: 1.1940x; 1.0041x over previous
//
#include <hip/hip_runtime.h>

#define DXYZ 128
#define NVERT (DXYZ * DXYZ * DXYZ)     // 2097152 voxels per (cloud,batch) grid
#define SBINS 128                       // bins per grid: 16(x) x 8(y), full z
#define RX 8                            // region x-extent  (bx = ix>>3, 16 bins)
#define RY 16                           // region y-extent  (by = iy>>4, 8 bins)
#define CHUNK 4096                      // points per hist/scatter block
#define PTHREADS 512                    // threads for hist/scatter blocks
#define MAXCHUNKS 1024                  // chunkscan LDS capacity

typedef float nf4 __attribute__((ext_vector_type(4)));  // native vec for builtins

// Record: 8 bytes.
//   lo = fx16 | fy16<<16                        (frac, 1/65536 fixed point)
//   hi = fz16 | (lx+1)<<16 | (ly+1)<<20 | iz<<25
// lx in [-1,7] rel. to bin x-origin, ly in [-1,15] rel. to bin y-origin,
// iz = absolute z voxel (7 bits). Regions span full z -> no z binning.

// ---------------- Pass 1: per-chunk LDS histogram ----------------
// bcnt layout: [key][chunk], key = cb*SBINS + (bx*8+by).
__global__ __launch_bounds__(PTHREADS) void hist2_kernel(
    const float* __restrict__ p0, const float* __restrict__ p1,
    unsigned* __restrict__ bcnt,
    int N, int B, int nchunks, int dup)
{
    __shared__ unsigned h[SBINS];
    for (int i = threadIdx.x; i < SBINS; i += PTHREADS) h[i] = 0u;
    __syncthreads();

    int blk = blockIdx.x;
    int cb = blk / nchunks;            // cloud*B + batch
    int c  = blk - cb * nchunks;       // chunk within slice
    const float* p = (cb < B ? p0 : p1) +
                     ((size_t)(cb % B) * N + (size_t)c * CHUNK) * 3;

    for (int i = threadIdx.x; i < CHUNK; i += PTHREADS) {
        float px = p[3*i+0] * 64.0f;
        float py = p[3*i+1] * 64.0f;
        int ix = (int)floorf(px) + 64;
        int iy = (int)floorf(py) + 64;
        int bx0 = ix >> 3, by0 = iy >> 4;
        int bx1 = (ix+1) >> 3, by1 = (iy+1) >> 4;
        if (!dup) { bx1 = bx0; by1 = by0; }
        for (int bx = bx0; bx <= bx1; ++bx)
            for (int by = by0; by <= by1; ++by)
                atomicAdd(&h[(bx << 3) + by], 1u);
    }
    __syncthreads();

    for (int k = threadIdx.x; k < SBINS; k += PTHREADS)
        bcnt[(size_t)(cb * SBINS + k) * nchunks + c] = h[k];
}

// ---------------- Pass 2a: per-key exclusive scan over chunks (in place) ----
__global__ __launch_bounds__(256) void chunkscan_kernel(
    unsigned* __restrict__ bcnt,         // [key][chunk] -> exclusive scan
    unsigned* __restrict__ keytotal,     // [key]
    int nchunks)
{
    __shared__ unsigned s[MAXCHUNKS];
    int key = blockIdx.x;
    unsigned* row = bcnt + (size_t)key * nchunks;

    for (int i = threadIdx.x; i < nchunks; i += 256) s[i] = row[i];
    __syncthreads();
    for (int off = 1; off < nchunks; off <<= 1) {
        unsigned v[MAXCHUNKS / 256];
        int nv = 0;
        for (int i = threadIdx.x; i < nchunks; i += 256)
            v[nv++] = (i >= off) ? s[i - off] : 0u;
        __syncthreads();
        nv = 0;
        for (int i = threadIdx.x; i < nchunks; i += 256)
            s[i] += v[nv++];
        __syncthreads();
    }
    for (int i = threadIdx.x; i < nchunks; i += 256)
        row[i] = (i == 0) ? 0u : s[i - 1];
    if (threadIdx.x == 0) keytotal[key] = s[nchunks - 1];
}

// ---------------- Pass 2b: exclusive scan over keys (1 block) ----------------
__global__ __launch_bounds__(1024) void scan_kernel(
    const unsigned* __restrict__ counts,
    unsigned* __restrict__ key_start,   // nkeys+1
    int nkeys)
{
    __shared__ unsigned part[1024];
    int tid = threadIdx.x;
    int chunk = (nkeys + 1023) / 1024;
    int lo = tid * chunk;
    unsigned s = 0;
    for (int i = 0; i < chunk; ++i) {
        int k = lo + i;
        if (k < nkeys) s += counts[k];
    }
    part[tid] = s;
    __syncthreads();
    for (int off = 1; off < 1024; off <<= 1) {
        unsigned v = (tid >= off) ? part[tid - off] : 0u;
        __syncthreads();
        part[tid] += v;
        __syncthreads();
    }
    unsigned run = (tid == 0) ? 0u : part[tid - 1];
    for (int i = 0; i < chunk; ++i) {
        int k = lo + i;
        if (k < nkeys) {
            key_start[k] = run;
            run += counts[k];
        }
    }
    if (tid == 1023) key_start[nkeys] = run;
}

// ---------------- Pass 3: scatter via LDS cursors ----------------
__global__ __launch_bounds__(PTHREADS) void scatter2_kernel(
    const float* __restrict__ p0, const float* __restrict__ p1,
    const unsigned* __restrict__ bscan,     // [key][chunk] exclusive per key
    const unsigned* __restrict__ keystart,  // [key]
    uint2* __restrict__ sorted, unsigned cap,
    int N, int B, int nchunks, int dup)
{
    __shared__ unsigned cur[SBINS];
    int blk = blockIdx.x;
    int cb = blk / nchunks;
    int c  = blk - cb * nchunks;
    for (int k = threadIdx.x; k < SBINS; k += PTHREADS) {
        int key = cb * SBINS + k;
        cur[k] = keystart[key] + bscan[(size_t)key * nchunks + c];
    }
    __syncthreads();

    const float* p = (cb < B ? p0 : p1) +
                     ((size_t)(cb % B) * N + (size_t)c * CHUNK) * 3;
    for (int i = threadIdx.x; i < CHUNK; i += PTHREADS) {
        float px = p[3*i+0] * 64.0f;
        float py = p[3*i+1] * 64.0f;
        float pz = p[3*i+2] * 64.0f;
        float lx = floorf(px), ly = floorf(py), lz = floorf(pz);
        int ix = (int)lx + 64, iy = (int)ly + 64, iz = (int)lz + 64;
        unsigned ex = min((unsigned)((px - lx) * 65536.0f), 65535u);
        unsigned ey = min((unsigned)((py - ly) * 65536.0f), 65535u);
        unsigned ez = min((unsigned)((pz - lz) * 65536.0f), 65535u);
        unsigned lo = ex | (ey << 16);
        int bx0 = ix >> 3, by0 = iy >> 4;
        int bx1 = (ix+1) >> 3, by1 = (iy+1) >> 4;
        if (!dup) { bx1 = bx0; by1 = by0; }
        for (int bx = bx0; bx <= bx1; ++bx)
            for (int by = by0; by <= by1; ++by) {
                unsigned llx = (unsigned)(ix - (bx << 3) + 1);  // [0,8]
                unsigned lly = (unsigned)(iy - (by << 4) + 1);  // [0,16]
                unsigned hi = ez | (llx << 16) | (lly << 20) |
                              ((unsigned)iz << 25);
                unsigned slot = atomicAdd(&cur[(bx << 3) + by], 1u);
                if (slot < cap) sorted[slot] = make_uint2(lo, hi);
            }
    }
}

// ---------------- Pass 4: per-slab gather + LDS accumulate ----------------
// One block per (cb, bx, by): accumulates an 8 x 16 x 128 slab (64 KB LDS)
// and writes it as 8 contiguous 8-KB chunks.
// NOTE: unsafeAtomicAdd -> native ds_add_f32. Plain atomicAdd(float*) compiles
// to a CAS loop without -munsafe-fp-atomics (the round-4..7 ~96us invariant).
__global__ __launch_bounds__(512) void gather3_kernel(
    const uint2* __restrict__ sorted,
    const unsigned* __restrict__ keystart,
    const unsigned* __restrict__ keytotal,
    float* __restrict__ out, int dup)
{
    __shared__ float acc[RX * RY * DXYZ];  // 64 KB: [cx][cy][cz]
    int g = blockIdx.x;
    int cb = g >> 7;                       // 128 bins per grid
    int r = g & (SBINS - 1);
    int rx = r >> 3, ry = r & 7;           // rx in [0,16), ry in [0,8)
    int x0 = rx << 3, y0 = ry << 4;

    nf4* a4 = (nf4*)acc;
    nf4 z4 = {0.f, 0.f, 0.f, 0.f};
    for (int i = threadIdx.x; i < RX * RY * DXYZ / 4; i += 512) a4[i] = z4;
    __syncthreads();

    int sxlo = dup ? rx : max(rx - 1, 0);
    int sylo = dup ? ry : max(ry - 1, 0);
    int kb = cb * SBINS;
    const float inv = 1.0f / 65536.0f;
    for (int sx = sxlo; sx <= rx; ++sx)
        for (int sy = sylo; sy <= ry; ++sy) {
            int gk = kb + (sx << 3) + sy;
            unsigned s = keystart[gk], e = s + keytotal[gk];
            int obx = ((sx - rx) << 3) - 1;   // bin-origin offset - 1
            int oby = ((sy - ry) << 4) - 1;
            for (unsigned i = s + threadIdx.x; i < e; i += 512) {
                uint2 rec = sorted[i];
                float fx = (float)(rec.x & 0xffffu) * inv;
                float fy = (float)(rec.x >> 16) * inv;
                float fz = (float)(rec.y & 0xffffu) * inv;
                int lx = (int)((rec.y >> 16) & 15u) + obx;
                int ly = (int)((rec.y >> 20) & 31u) + oby;
                int zc = (int)(rec.y >> 25);
                float gx[2] = {1.0f - fx, fx};
                float gy[2] = {1.0f - fy, fy};
                float gz[2] = {1.0f - fz, fz};
#pragma unroll
                for (int dx = 0; dx < 2; ++dx) {
                    int cx = lx + dx;
                    if ((unsigned)cx >= (unsigned)RX) continue;
#pragma unroll
                    for (int dy = 0; dy < 2; ++dy) {
                        int cy = ly + dy;
                        if ((unsigned)cy >= (unsigned)RY) continue;
#pragma unroll
                        for (int dz = 0; dz < 2; ++dz) {
                            int cz = zc + dz;
                            if ((unsigned)cz >= (unsigned)DXYZ) continue;
                            unsafeAtomicAdd(&acc[((cx << 4) + cy) * DXYZ + cz],
                                            gx[dx] * gy[dy] * gz[dz]);
                        }
                    }
                }
            }
        }
    __syncthreads();

    // Epilogue: 8 contiguous 8-KB chunks (one per x-plane of the slab).
    float* ob = out + (size_t)cb * NVERT;
    int tid = threadIdx.x;
#pragma unroll
    for (int cx = 0; cx < RX; ++cx) {
        size_t base = (((size_t)(x0 + cx) * DXYZ) + (size_t)y0) * DXYZ;
        nf4* dst = (nf4*)(ob + base);
        const nf4* src = (const nf4*)&acc[cx * (RY * DXYZ)];
        __builtin_nontemporal_store(src[tid], &dst[tid]);  // 512 f4 = 8 KB
    }
}

// ---------------- Fallback: direct atomic splat ----------------
__global__ __launch_bounds__(256) void splat_kernel(
    const float* __restrict__ pts, float* __restrict__ out,
    int n_per_batch, int total)
{
    int t = blockIdx.x * blockDim.x + threadIdx.x;
    if (t >= total) return;
    float px = pts[3*t+0] * 64.0f, py = pts[3*t+1] * 64.0f, pz = pts[3*t+2] * 64.0f;
    float lx = floorf(px), ly = floorf(py), lz = floorf(pz);
    float fx = px - lx, fy = py - ly, fz = pz - lz;
    int ix = (int)lx + 64, iy = (int)ly + 64, iz = (int)lz + 64;
    int b = t / n_per_batch;
    float* o = out + (size_t)b * NVERT;
    size_t base = ((size_t)ix * DXYZ + (size_t)iy) * DXYZ + (size_t)iz;
    float gx[2] = {1.0f-fx, fx}, gy[2] = {1.0f-fy, fy}, gz[2] = {1.0f-fz, fz};
#pragma unroll
    for (int dx = 0; dx < 2; ++dx)
#pragma unroll
        for (int dy = 0; dy < 2; ++dy)
#pragma unroll
            for (int dz = 0; dz < 2; ++dz)
                unsafeAtomicAdd(o + base + (size_t)dx * (DXYZ*DXYZ) + dy * DXYZ + dz,
                                gx[dx] * gy[dy] * gz[dz]);
}

static inline size_t align256(size_t x) { return (x + 255) & ~(size_t)255; }

extern "C" void kernel_launch(void* const* d_in, const int* in_sizes, int n_in,
                              void* d_out, int out_size, void* d_ws, size_t ws_size,
                              hipStream_t stream) {
    const float* pred = (const float*)d_in[0];
    const float* gt   = (const float*)d_in[1];
    float* out = (float*)d_out;

    int total = in_sizes[0] / 3;           // B*N points per cloud
    int B = out_size / (2 * NVERT);
    int N = total / B;
    int CB = 2 * B;
    int nchunks = N / CHUNK;
    int nkeys = CB * SBINS;
    int nblocks = CB * nchunks;
    size_t points_all = (size_t)2 * total;
    bool divisible = (N % CHUNK) == 0 && N > 0 && nchunks <= MAXCHUNKS;

    // Workspace layout
    size_t off_keytotal = 0;
    size_t off_keystart = align256((size_t)nkeys * 4);
    size_t off_bcnt     = off_keystart + align256(((size_t)nkeys + 1) * 4);
    size_t mat_bytes    = align256((size_t)nkeys * nchunks * 4);
    size_t off_sorted   = off_bcnt + mat_bytes;
    size_t cap = (ws_size > off_sorted) ? (ws_size - off_sorted) / sizeof(uint2) : 0;

    // dup path duplicates each point into every (x,y) bin it touches
    // (E[x] ~= 1.20 for uniform inputs); 1.5x capacity is a huge margin.
    bool can_dup   = divisible && cap >= points_all + points_all / 2;
    bool can_nodup = divisible && cap >= points_all;

    if (!can_nodup) {
        (void)hipMemsetAsync(d_out, 0, (size_t)out_size * sizeof(float), stream);
        int blocks = (total + 255) / 256;
        splat_kernel<<<blocks, 256, 0, stream>>>(pred, out, N, total);
        splat_kernel<<<blocks, 256, 0, stream>>>(gt, out + (size_t)B * NVERT, N, total);
        return;
    }
    int dup = can_dup ? 1 : 0;

    char* ws = (char*)d_ws;
    unsigned* keytotal = (unsigned*)(ws + off_keytotal);
    unsigned* keystart = (unsigned*)(ws + off_keystart);
    unsigned* bcnt     = (unsigned*)(ws + off_bcnt);
    uint2*    sorted   = (uint2*)(ws + off_sorted);

    hist2_kernel<<<nblocks, PTHREADS, 0, stream>>>(pred, gt, bcnt, N, B,
                                                   nchunks, dup);
    chunkscan_kernel<<<nkeys, 256, 0, stream>>>(bcnt, keytotal, nchunks);
    scan_kernel<<<1, 1024, 0, stream>>>(keytotal, keystart, nkeys);
    scatter2_kernel<<<nblocks, PTHREADS, 0, stream>>>(pred, gt, bcnt, keystart,
                                                      sorted, (unsigned)cap,
                                                      N, B, nchunks, dup);
    gather3_kernel<<<nkeys, 512, 0, stream>>>(sorted, keystart, keytotal,
                                              out, dup);
}

// Round 9
// 124.613 us; speedup vs baseline: 1.9041x; 1.5946x over previous
//
#include <hip/hip_runtime.h>

#define DXYZ 128
#define NVERT (DXYZ * DXYZ * DXYZ)     // 2097152 voxels per (cloud,batch) grid
#define SBINS 128                       // bins per grid: 16(x) x 8(y), full z
#define RX 8                            // region x-extent  (bx = ix>>3, 16 bins)
#define RY 16                           // region y-extent  (by = iy>>4, 8 bins)
#define CHUNK 4096                      // points per hist/scatter block
#define PTHREADS 512                    // threads for hist/scatter blocks
#define MAXCHUNKS 1024                  // chunkscan LDS capacity
#define FIX 16777216.0f                 // 2^24 fixed-point scale
#define INVFIX (1.0f / 16777216.0f)

typedef float nf4 __attribute__((ext_vector_type(4)));  // native vec for builtins

// Record: 8 bytes.
//   lo = fx16 | fy16<<16                        (frac, 1/65536 fixed point)
//   hi = fz16 | (lx+1)<<16 | (ly+1)<<20 | iz<<25
// lx in [-1,7] rel. to bin x-origin, ly in [-1,15] rel. to bin y-origin,
// iz = absolute z voxel (7 bits). Regions span full z -> no z binning.

// ---------------- Pass 1: per-chunk LDS histogram ----------------
// bcnt layout: [key][chunk], key = cb*SBINS + (bx*8+by).
__global__ __launch_bounds__(PTHREADS) void hist2_kernel(
    const float* __restrict__ p0, const float* __restrict__ p1,
    unsigned* __restrict__ bcnt,
    int N, int B, int nchunks, int dup)
{
    __shared__ unsigned h[SBINS];
    for (int i = threadIdx.x; i < SBINS; i += PTHREADS) h[i] = 0u;
    __syncthreads();

    int blk = blockIdx.x;
    int cb = blk / nchunks;            // cloud*B + batch
    int c  = blk - cb * nchunks;       // chunk within slice
    const float* p = (cb < B ? p0 : p1) +
                     ((size_t)(cb % B) * N + (size_t)c * CHUNK) * 3;

    for (int i = threadIdx.x; i < CHUNK; i += PTHREADS) {
        float px = p[3*i+0] * 64.0f;
        float py = p[3*i+1] * 64.0f;
        int ix = (int)floorf(px) + 64;
        int iy = (int)floorf(py) + 64;
        int bx0 = ix >> 3, by0 = iy >> 4;
        int bx1 = (ix+1) >> 3, by1 = (iy+1) >> 4;
        if (!dup) { bx1 = bx0; by1 = by0; }
        for (int bx = bx0; bx <= bx1; ++bx)
            for (int by = by0; by <= by1; ++by)
                atomicAdd(&h[(bx << 3) + by], 1u);
    }
    __syncthreads();

    for (int k = threadIdx.x; k < SBINS; k += PTHREADS)
        bcnt[(size_t)(cb * SBINS + k) * nchunks + c] = h[k];
}

// ---------------- Pass 2a: per-key exclusive scan over chunks (in place) ----
__global__ __launch_bounds__(256) void chunkscan_kernel(
    unsigned* __restrict__ bcnt,         // [key][chunk] -> exclusive scan
    unsigned* __restrict__ keytotal,     // [key]
    int nchunks)
{
    __shared__ unsigned s[MAXCHUNKS];
    int key = blockIdx.x;
    unsigned* row = bcnt + (size_t)key * nchunks;

    for (int i = threadIdx.x; i < nchunks; i += 256) s[i] = row[i];
    __syncthreads();
    for (int off = 1; off < nchunks; off <<= 1) {
        unsigned v[MAXCHUNKS / 256];
        int nv = 0;
        for (int i = threadIdx.x; i < nchunks; i += 256)
            v[nv++] = (i >= off) ? s[i - off] : 0u;
        __syncthreads();
        nv = 0;
        for (int i = threadIdx.x; i < nchunks; i += 256)
            s[i] += v[nv++];
        __syncthreads();
    }
    for (int i = threadIdx.x; i < nchunks; i += 256)
        row[i] = (i == 0) ? 0u : s[i - 1];
    if (threadIdx.x == 0) keytotal[key] = s[nchunks - 1];
}

// ---------------- Pass 2b: exclusive scan over keys (1 block) ----------------
__global__ __launch_bounds__(1024) void scan_kernel(
    const unsigned* __restrict__ counts,
    unsigned* __restrict__ key_start,   // nkeys+1
    int nkeys)
{
    __shared__ unsigned part[1024];
    int tid = threadIdx.x;
    int chunk = (nkeys + 1023) / 1024;
    int lo = tid * chunk;
    unsigned s = 0;
    for (int i = 0; i < chunk; ++i) {
        int k = lo + i;
        if (k < nkeys) s += counts[k];
    }
    part[tid] = s;
    __syncthreads();
    for (int off = 1; off < 1024; off <<= 1) {
        unsigned v = (tid >= off) ? part[tid - off] : 0u;
        __syncthreads();
        part[tid] += v;
        __syncthreads();
    }
    unsigned run = (tid == 0) ? 0u : part[tid - 1];
    for (int i = 0; i < chunk; ++i) {
        int k = lo + i;
        if (k < nkeys) {
            key_start[k] = run;
            run += counts[k];
        }
    }
    if (tid == 1023) key_start[nkeys] = run;
}

// ---------------- Pass 3: scatter via LDS cursors ----------------
__global__ __launch_bounds__(PTHREADS) void scatter2_kernel(
    const float* __restrict__ p0, const float* __restrict__ p1,
    const unsigned* __restrict__ bscan,     // [key][chunk] exclusive per key
    const unsigned* __restrict__ keystart,  // [key]
    uint2* __restrict__ sorted, unsigned cap,
    int N, int B, int nchunks, int dup)
{
    __shared__ unsigned cur[SBINS];
    int blk = blockIdx.x;
    int cb = blk / nchunks;
    int c  = blk - cb * nchunks;
    for (int k = threadIdx.x; k < SBINS; k += PTHREADS) {
        int key = cb * SBINS + k;
        cur[k] = keystart[key] + bscan[(size_t)key * nchunks + c];
    }
    __syncthreads();

    const float* p = (cb < B ? p0 : p1) +
                     ((size_t)(cb % B) * N + (size_t)c * CHUNK) * 3;
    for (int i = threadIdx.x; i < CHUNK; i += PTHREADS) {
        float px = p[3*i+0] * 64.0f;
        float py = p[3*i+1] * 64.0f;
        float pz = p[3*i+2] * 64.0f;
        float lx = floorf(px), ly = floorf(py), lz = floorf(pz);
        int ix = (int)lx + 64, iy = (int)ly + 64, iz = (int)lz + 64;
        unsigned ex = min((unsigned)((px - lx) * 65536.0f), 65535u);
        unsigned ey = min((unsigned)((py - ly) * 65536.0f), 65535u);
        unsigned ez = min((unsigned)((pz - lz) * 65536.0f), 65535u);
        unsigned lo = ex | (ey << 16);
        int bx0 = ix >> 3, by0 = iy >> 4;
        int bx1 = (ix+1) >> 3, by1 = (iy+1) >> 4;
        if (!dup) { bx1 = bx0; by1 = by0; }
        for (int bx = bx0; bx <= bx1; ++bx)
            for (int by = by0; by <= by1; ++by) {
                unsigned llx = (unsigned)(ix - (bx << 3) + 1);  // [0,8]
                unsigned lly = (unsigned)(iy - (by << 4) + 1);  // [0,16]
                unsigned hi = ez | (llx << 16) | (lly << 20) |
                              ((unsigned)iz << 25);
                unsigned slot = atomicAdd(&cur[(bx << 3) + by], 1u);
                if (slot < cap) sorted[slot] = make_uint2(lo, hi);
            }
    }
}

// ---------------- Pass 4: per-slab gather, FIXED-POINT LDS accumulate ------
// One block per (cb, bx, by): accumulates an 8 x 16 x 128 slab (64 KB LDS)
// in 24.8 fixed point via native ds_add_u32 (f32 LDS atomicAdd lowers to a
// CAS/latency loop without -munsafe-fp-atomics -- the rounds-4..8 ~96us
// invariant), then converts and writes 8 contiguous 8-KB chunks.
__global__ __launch_bounds__(512) void gather3_kernel(
    const uint2* __restrict__ sorted,
    const unsigned* __restrict__ keystart,
    const unsigned* __restrict__ keytotal,
    float* __restrict__ out, int dup)
{
    __shared__ unsigned acc[RX * RY * DXYZ];  // 64 KB: [cx][cy][cz], 24.8 fixed
    int g = blockIdx.x;
    int cb = g >> 7;                       // 128 bins per grid
    int r = g & (SBINS - 1);
    int rx = r >> 3, ry = r & 7;           // rx in [0,16), ry in [0,8)
    int x0 = rx << 3, y0 = ry << 4;

    uint4* a4 = (uint4*)acc;
    uint4 z4 = make_uint4(0u, 0u, 0u, 0u);
    for (int i = threadIdx.x; i < RX * RY * DXYZ / 4; i += 512) a4[i] = z4;
    __syncthreads();

    int sxlo = dup ? rx : max(rx - 1, 0);
    int sylo = dup ? ry : max(ry - 1, 0);
    int kb = cb * SBINS;
    const float inv = 1.0f / 65536.0f;
    for (int sx = sxlo; sx <= rx; ++sx)
        for (int sy = sylo; sy <= ry; ++sy) {
            int gk = kb + (sx << 3) + sy;
            unsigned s = keystart[gk], e = s + keytotal[gk];
            int obx = ((sx - rx) << 3) - 1;   // bin-origin offset - 1
            int oby = ((sy - ry) << 4) - 1;
            for (unsigned i = s + threadIdx.x; i < e; i += 512) {
                uint2 rec = sorted[i];
                float fx = (float)(rec.x & 0xffffu) * inv;
                float fy = (float)(rec.x >> 16) * inv;
                float fz = (float)(rec.y & 0xffffu) * inv;
                int lx = (int)((rec.y >> 16) & 15u) + obx;
                int ly = (int)((rec.y >> 20) & 31u) + oby;
                int zc = (int)(rec.y >> 25);
                float gx[2] = {1.0f - fx, fx};
                float gy[2] = {1.0f - fy, fy};
                float gz[2] = {1.0f - fz, fz};
#pragma unroll
                for (int dx = 0; dx < 2; ++dx) {
                    int cx = lx + dx;
                    if ((unsigned)cx >= (unsigned)RX) continue;
#pragma unroll
                    for (int dy = 0; dy < 2; ++dy) {
                        int cy = ly + dy;
                        if ((unsigned)cy >= (unsigned)RY) continue;
#pragma unroll
                        for (int dz = 0; dz < 2; ++dz) {
                            int cz = zc + dz;
                            if ((unsigned)cz >= (unsigned)DXYZ) continue;
                            unsigned w = (unsigned)(gx[dx] * gy[dy] * gz[dz]
                                                    * FIX + 0.5f);
                            atomicAdd(&acc[((cx << 4) + cy) * DXYZ + cz], w);
                        }
                    }
                }
            }
        }
    __syncthreads();

    // Epilogue: convert fixed->float, 8 contiguous 8-KB chunks.
    float* ob = out + (size_t)cb * NVERT;
    int tid = threadIdx.x;
#pragma unroll
    for (int cx = 0; cx < RX; ++cx) {
        size_t base = (((size_t)(x0 + cx) * DXYZ) + (size_t)y0) * DXYZ;
        nf4* dst = (nf4*)(ob + base);
        const uint4* src = (const uint4*)&acc[cx * (RY * DXYZ)];
        uint4 u = src[tid];
        nf4 f = {(float)u.x * INVFIX, (float)u.y * INVFIX,
                 (float)u.z * INVFIX, (float)u.w * INVFIX};
        __builtin_nontemporal_store(f, &dst[tid]);  // 512 f4 = 8 KB
    }
}

// ---------------- Fallback: direct atomic splat ----------------
__global__ __launch_bounds__(256) void splat_kernel(
    const float* __restrict__ pts, float* __restrict__ out,
    int n_per_batch, int total)
{
    int t = blockIdx.x * blockDim.x + threadIdx.x;
    if (t >= total) return;
    float px = pts[3*t+0] * 64.0f, py = pts[3*t+1] * 64.0f, pz = pts[3*t+2] * 64.0f;
    float lx = floorf(px), ly = floorf(py), lz = floorf(pz);
    float fx = px - lx, fy = py - ly, fz = pz - lz;
    int ix = (int)lx + 64, iy = (int)ly + 64, iz = (int)lz + 64;
    int b = t / n_per_batch;
    float* o = out + (size_t)b * NVERT;
    size_t base = ((size_t)ix * DXYZ + (size_t)iy) * DXYZ + (size_t)iz;
    float gx[2] = {1.0f-fx, fx}, gy[2] = {1.0f-fy, fy}, gz[2] = {1.0f-fz, fz};
#pragma unroll
    for (int dx = 0; dx < 2; ++dx)
#pragma unroll
        for (int dy = 0; dy < 2; ++dy)
#pragma unroll
            for (int dz = 0; dz < 2; ++dz)
                atomicAdd(o + base + (size_t)dx * (DXYZ*DXYZ) + dy * DXYZ + dz,
                          gx[dx] * gy[dy] * gz[dz]);
}

static inline size_t align256(size_t x) { return (x + 255) & ~(size_t)255; }

extern "C" void kernel_launch(void* const* d_in, const int* in_sizes, int n_in,
                              void* d_out, int out_size, void* d_ws, size_t ws_size,
                              hipStream_t stream) {
    const float* pred = (const float*)d_in[0];
    const float* gt   = (const float*)d_in[1];
    float* out = (float*)d_out;

    int total = in_sizes[0] / 3;           // B*N points per cloud
    int B = out_size / (2 * NVERT);
    int N = total / B;
    int CB = 2 * B;
    int nchunks = N / CHUNK;
    int nkeys = CB * SBINS;
    int nblocks = CB * nchunks;
    size_t points_all = (size_t)2 * total;
    bool divisible = (N % CHUNK) == 0 && N > 0 && nchunks <= MAXCHUNKS;

    // Workspace layout
    size_t off_keytotal = 0;
    size_t off_keystart = align256((size_t)nkeys * 4);
    size_t off_bcnt     = off_keystart + align256(((size_t)nkeys + 1) * 4);
    size_t mat_bytes    = align256((size_t)nkeys * nchunks * 4);
    size_t off_sorted   = off_bcnt + mat_bytes;
    size_t cap = (ws_size > off_sorted) ? (ws_size - off_sorted) / sizeof(uint2) : 0;

    // dup path duplicates each point into every (x,y) bin it touches
    // (E[x] ~= 1.20 for uniform inputs); 1.5x capacity is a huge margin.
    bool can_dup   = divisible && cap >= points_all + points_all / 2;
    bool can_nodup = divisible && cap >= points_all;

    if (!can_nodup) {
        (void)hipMemsetAsync(d_out, 0, (size_t)out_size * sizeof(float), stream);
        int blocks = (total + 255) / 256;
        splat_kernel<<<blocks, 256, 0, stream>>>(pred, out, N, total);
        splat_kernel<<<blocks, 256, 0, stream>>>(gt, out + (size_t)B * NVERT, N, total);
        return;
    }
    int dup = can_dup ? 1 : 0;

    char* ws = (char*)d_ws;
    unsigned* keytotal = (unsigned*)(ws + off_keytotal);
    unsigned* keystart = (unsigned*)(ws + off_keystart);
    unsigned* bcnt     = (unsigned*)(ws + off_bcnt);
    uint2*    sorted   = (uint2*)(ws + off_sorted);

    hist2_kernel<<<nblocks, PTHREADS, 0, stream>>>(pred, gt, bcnt, N, B,
                                                   nchunks, dup);
    chunkscan_kernel<<<nkeys, 256, 0, stream>>>(bcnt, keytotal, nchunks);
    scan_kernel<<<1, 1024, 0, stream>>>(keytotal, keystart, nkeys);
    scatter2_kernel<<<nblocks, PTHREADS, 0, stream>>>(pred, gt, bcnt, keystart,
                                                      sorted, (unsigned)cap,
                                                      N, B, nchunks, dup);
    gather3_kernel<<<nkeys, 512, 0, stream>>>(sorted, keystart, keytotal,
                                              out, dup);
}

// Round 10
// 116.540 us; speedup vs baseline: 2.0360x; 1.0693x over previous
//
#include <hip/hip_runtime.h>

#define DXYZ 128
#define NVERT (DXYZ * DXYZ * DXYZ)     // 2097152 voxels per (cloud,batch) grid
#define SBINS 128                       // bins per grid: 16(x) x 8(y), full z
#define RX 8                            // region x-extent  (bx = ix>>3)
#define RY 16                           // region y-extent  (by = iy>>4)
#define CHUNK 4096                      // points per scatter block
#define PTHREADS 512
#define FIX 16777216.0f                 // 2^24 fixed-point scale
#define INVFIX (1.0f / 16777216.0f)

typedef float nf4 __attribute__((ext_vector_type(4)));

// Record: 8 bytes.
//   lo = fx16 | fy16<<16                        (frac, 1/65536 fixed point)
//   hi = fz16 | (lx+1)<<16 | (ly+1)<<20 | iz<<25
// lx in [-1,7] rel. to bin x-origin, ly in [-1,15] rel. to bin y-origin,
// iz = absolute z voxel (7 bits).

// -------- Single-pass scatter: LDS hist -> segment reservation -> emit -----
// Buckets: sorted[key][capacity]; per-key fill counts in gcnt (zeroed before).
// Order within a bucket is nondeterministic, but gather accumulates in
// integer fixed point (commutative) -> output is still deterministic.
__global__ __launch_bounds__(PTHREADS) void scatter_onepass(
    const float* __restrict__ p0, const float* __restrict__ p1,
    unsigned* __restrict__ gcnt,        // [nkeys], pre-zeroed
    uint2* __restrict__ sorted,         // [nkeys][capacity]
    int N, int B, int nchunks, unsigned capacity)
{
    __shared__ unsigned h[SBINS];
    __shared__ unsigned cur[SBINS];

    int blk = blockIdx.x;
    int cb = blk / nchunks;            // cloud*B + batch
    int c  = blk - cb * nchunks;
    const float* p = (cb < B ? p0 : p1) +
                     ((size_t)(cb % B) * N + (size_t)c * CHUNK) * 3;

    for (int i = threadIdx.x; i < SBINS; i += PTHREADS) h[i] = 0u;
    __syncthreads();

    // Phase A: per-chunk histogram over (x,y) bins, with corner duplication.
    for (int i = threadIdx.x; i < CHUNK; i += PTHREADS) {
        float px = p[3*i+0] * 64.0f;
        float py = p[3*i+1] * 64.0f;
        int ix = (int)floorf(px) + 64;
        int iy = (int)floorf(py) + 64;
        int bx0 = ix >> 3, by0 = iy >> 4;
        int bx1 = (ix+1) >> 3, by1 = (iy+1) >> 4;
        for (int bx = bx0; bx <= bx1; ++bx)
            for (int by = by0; by <= by1; ++by)
                atomicAdd(&h[(bx << 3) + by], 1u);
    }
    __syncthreads();

    // Phase B: reserve a contiguous segment of each touched bucket.
    for (int k = threadIdx.x; k < SBINS; k += PTHREADS)
        cur[k] = atomicAdd(&gcnt[cb * SBINS + k], h[k]);
    __syncthreads();

    // Phase C: emit records (chunk re-read is L2-hot).
    for (int i = threadIdx.x; i < CHUNK; i += PTHREADS) {
        float px = p[3*i+0] * 64.0f;
        float py = p[3*i+1] * 64.0f;
        float pz = p[3*i+2] * 64.0f;
        float lx = floorf(px), ly = floorf(py), lz = floorf(pz);
        int ix = (int)lx + 64, iy = (int)ly + 64, iz = (int)lz + 64;
        unsigned ex = min((unsigned)((px - lx) * 65536.0f), 65535u);
        unsigned ey = min((unsigned)((py - ly) * 65536.0f), 65535u);
        unsigned ez = min((unsigned)((pz - lz) * 65536.0f), 65535u);
        unsigned lo = ex | (ey << 16);
        int bx0 = ix >> 3, by0 = iy >> 4;
        int bx1 = (ix+1) >> 3, by1 = (iy+1) >> 4;
        for (int bx = bx0; bx <= bx1; ++bx)
            for (int by = by0; by <= by1; ++by) {
                unsigned llx = (unsigned)(ix - (bx << 3) + 1);  // [0,8]
                unsigned lly = (unsigned)(iy - (by << 4) + 1);  // [0,16]
                unsigned hi = ez | (llx << 16) | (lly << 20) |
                              ((unsigned)iz << 25);
                int k = (bx << 3) + by;
                unsigned slot = atomicAdd(&cur[k], 1u);
                if (slot < capacity)
                    sorted[(size_t)(cb * SBINS + k) * capacity + slot] =
                        make_uint2(lo, hi);
            }
    }
}

// -------- Gather: per-slab fixed-point LDS accumulate + contiguous store ---
// One block per (cb, bx, by): 8 x 16 x 128 slab (64 KB LDS) in 24.8 fixed
// point via native ds_add_u32 (f32 LDS atomicAdd would CAS-loop without
// -munsafe-fp-atomics -- the rounds-4..8 ~96us invariant).
__global__ __launch_bounds__(512) void gather3_kernel(
    const uint2* __restrict__ sorted,
    const unsigned* __restrict__ gcnt,
    float* __restrict__ out, unsigned capacity)
{
    __shared__ unsigned acc[RX * RY * DXYZ];  // 64 KB: [cx][cy][cz]
    int g = blockIdx.x;
    int cb = g >> 7;
    int r = g & (SBINS - 1);
    int rx = r >> 3, ry = r & 7;
    int x0 = rx << 3, y0 = ry << 4;

    uint4* a4 = (uint4*)acc;
    uint4 z4 = make_uint4(0u, 0u, 0u, 0u);
    for (int i = threadIdx.x; i < RX * RY * DXYZ / 4; i += 512) a4[i] = z4;
    __syncthreads();

    const float inv = 1.0f / 65536.0f;
    unsigned cnt = min(gcnt[g], capacity);
    size_t s = (size_t)g * capacity;
    for (unsigned i = threadIdx.x; i < cnt; i += 512) {
        uint2 rec = sorted[s + i];
        float fx = (float)(rec.x & 0xffffu) * inv;
        float fy = (float)(rec.x >> 16) * inv;
        float fz = (float)(rec.y & 0xffffu) * inv;
        int lx = (int)((rec.y >> 16) & 15u) - 1;
        int ly = (int)((rec.y >> 20) & 31u) - 1;
        int zc = (int)(rec.y >> 25);
        float gx[2] = {1.0f - fx, fx};
        float gy[2] = {1.0f - fy, fy};
        float gz[2] = {1.0f - fz, fz};
#pragma unroll
        for (int dx = 0; dx < 2; ++dx) {
            int cx = lx + dx;
            if ((unsigned)cx >= (unsigned)RX) continue;
#pragma unroll
            for (int dy = 0; dy < 2; ++dy) {
                int cy = ly + dy;
                if ((unsigned)cy >= (unsigned)RY) continue;
#pragma unroll
                for (int dz = 0; dz < 2; ++dz) {
                    int cz = zc + dz;
                    if ((unsigned)cz >= (unsigned)DXYZ) continue;
                    unsigned w = (unsigned)(gx[dx] * gy[dy] * gz[dz]
                                            * FIX + 0.5f);
                    atomicAdd(&acc[((cx << 4) + cy) * DXYZ + cz], w);
                }
            }
        }
    }
    __syncthreads();

    // Epilogue: convert fixed->float, 8 contiguous 8-KB chunks.
    float* ob = out + (size_t)cb * NVERT;
    int tid = threadIdx.x;
#pragma unroll
    for (int cx = 0; cx < RX; ++cx) {
        size_t base = (((size_t)(x0 + cx) * DXYZ) + (size_t)y0) * DXYZ;
        nf4* dst = (nf4*)(ob + base);
        const uint4* src = (const uint4*)&acc[cx * (RY * DXYZ)];
        uint4 u = src[tid];
        nf4 f = {(float)u.x * INVFIX, (float)u.y * INVFIX,
                 (float)u.z * INVFIX, (float)u.w * INVFIX};
        __builtin_nontemporal_store(f, &dst[tid]);
    }
}

// ---------------- Fallback: direct atomic splat ----------------
__global__ __launch_bounds__(256) void splat_kernel(
    const float* __restrict__ pts, float* __restrict__ out,
    int n_per_batch, int total)
{
    int t = blockIdx.x * blockDim.x + threadIdx.x;
    if (t >= total) return;
    float px = pts[3*t+0] * 64.0f, py = pts[3*t+1] * 64.0f, pz = pts[3*t+2] * 64.0f;
    float lx = floorf(px), ly = floorf(py), lz = floorf(pz);
    float fx = px - lx, fy = py - ly, fz = pz - lz;
    int ix = (int)lx + 64, iy = (int)ly + 64, iz = (int)lz + 64;
    int b = t / n_per_batch;
    float* o = out + (size_t)b * NVERT;
    size_t base = ((size_t)ix * DXYZ + (size_t)iy) * DXYZ + (size_t)iz;
    float gx[2] = {1.0f-fx, fx}, gy[2] = {1.0f-fy, fy}, gz[2] = {1.0f-fz, fz};
#pragma unroll
    for (int dx = 0; dx < 2; ++dx)
#pragma unroll
        for (int dy = 0; dy < 2; ++dy)
#pragma unroll
            for (int dz = 0; dz < 2; ++dz)
                atomicAdd(o + base + (size_t)dx * (DXYZ*DXYZ) + dy * DXYZ + dz,
                          gx[dx] * gy[dy] * gz[dz]);
}

static inline size_t align256(size_t x) { return (x + 255) & ~(size_t)255; }

extern "C" void kernel_launch(void* const* d_in, const int* in_sizes, int n_in,
                              void* d_out, int out_size, void* d_ws, size_t ws_size,
                              hipStream_t stream) {
    const float* pred = (const float*)d_in[0];
    const float* gt   = (const float*)d_in[1];
    float* out = (float*)d_out;

    int total = in_sizes[0] / 3;           // B*N points per cloud
    int B = out_size / (2 * NVERT);
    int N = total / B;
    int CB = 2 * B;
    int nchunks = N / CHUNK;
    int nkeys = CB * SBINS;
    int nblocks = CB * nchunks;
    bool divisible = (N % CHUNK) == 0 && N > 0;

    // Bucket capacity: 2x the dup-inflated per-key mean (E[dup]~=1.2,
    // sigma ~= sqrt(mean) -> 2x mean is a >30-sigma margin), 256-aligned.
    unsigned mean = (unsigned)(((size_t)N * 5 / 4) / SBINS);
    unsigned capacity = ((mean * 2) + 255u) & ~255u;
    if (capacity < 1024u) capacity = 1024u;

    size_t off_gcnt   = 0;
    size_t off_sorted = align256((size_t)nkeys * 4);
    size_t need = off_sorted + (size_t)nkeys * capacity * sizeof(uint2);

    if (!divisible || ws_size < need) {
        (void)hipMemsetAsync(d_out, 0, (size_t)out_size * sizeof(float), stream);
        int blocks = (total + 255) / 256;
        splat_kernel<<<blocks, 256, 0, stream>>>(pred, out, N, total);
        splat_kernel<<<blocks, 256, 0, stream>>>(gt, out + (size_t)B * NVERT, N, total);
        return;
    }

    char* ws = (char*)d_ws;
    unsigned* gcnt = (unsigned*)(ws + off_gcnt);
    uint2*    sorted = (uint2*)(ws + off_sorted);

    (void)hipMemsetAsync(gcnt, 0, (size_t)nkeys * 4, stream);
    scatter_onepass<<<nblocks, PTHREADS, 0, stream>>>(pred, gt, gcnt, sorted,
                                                      N, B, nchunks, capacity);
    gather3_kernel<<<nkeys, 512, 0, stream>>>(sorted, gcnt, out, capacity);
}